// Round 4
// baseline (643.743 us; speedup 1.0000x reference)
//
#include <hip/hip_runtime.h>
#include <math.h>

#define D 64
#define H 128
#define KIN 8
#define KOUT 4
#define NPB 16                 // nodes per block
#define ROWS (NPB*KOUT)        // 64 MLP rows per block
#define THREADS 256
#define WAVES 4
#define NPW (NPB/WAVES)        // 4 nodes per wave (2 iters x 2 nodes)
#define XLDB 136               // xbuf leading dim bf16 (272B: 16B shift/row -> 2-way, free)
#define ELD16 72               // eins leading dim bf16 (144B: 4-bank shift/row)

typedef __attribute__((ext_vector_type(8))) short short8v;  // 8 bf16 = 4 VGPR
typedef __attribute__((ext_vector_type(4))) float f32x4;

__device__ inline unsigned short f2bf(float f) {            // RNE float->bf16
    union { float f; unsigned u; } v; v.f = f;
    unsigned r = v.u + 0x7FFF + ((v.u >> 16) & 1);
    return (unsigned short)(r >> 16);
}

// ---- weight pre-conversion: W0,W1 (fp32, 128x128 each) -> bf16 in ws ----
__global__ void convert_w_kernel(const float* __restrict__ W0,
                                 const float* __restrict__ W1,
                                 unsigned short* __restrict__ Wbf) {
    const int i = blockIdx.x * 256 + threadIdx.x;           // 0 .. 32767
    const float v = (i < H*H) ? W0[i] : W1[i - H*H];
    Wbf[i] = f2bf(v);
}

__global__ __launch_bounds__(THREADS, 4) void encoder_kernel(
    const float* __restrict__ edges,
    const int*   __restrict__ in_idx,
    const int*   __restrict__ in_mask,
    const int*   __restrict__ out_idx,
    const int*   __restrict__ out_mask,
    const float* __restrict__ b0, const float* __restrict__ b1,
    const float* __restrict__ Wout, const float* __restrict__ bout,
    const unsigned short* __restrict__ Wbf,   // [2][128][128] bf16
    float* __restrict__ out, int N)
{
    __shared__ __align__(16) unsigned short xbuf[ROWS][XLDB];    // 17408 B
    __shared__ __align__(16) unsigned short eins[WAVES][16][ELD16]; // 9216 B
    __shared__ float omaskf[ROWS];                               //   256 B

    const int tid  = threadIdx.x;
    const int wave = tid >> 6;
    const int lane = tid & 63;
    const int nodeBase = blockIdx.x * NPB;

    const int col = lane & 15;     // MFMA col (key index over 2 nodes)
    const int grp = lane >> 4;     // 0..3 (row group)

    // ---------------- Phase 1: attention + pooling, 2 nodes per iteration ----
    for (int it = 0; it < 2; ++it) {
        const int nl0 = wave * NPW + it * 2;   // local node pair base
        const int n0  = nodeBase + nl0;        // N%16==0 -> always valid

        // one coalesced load each; values distributed by shuffle
        const int   idx_l  = in_idx [n0*KIN  + col];          // 16 in-edge idx
        const float mkcol  = (float)in_mask[n0*KIN  + col];   // key mask at col
        const int   oidx_l = out_idx[n0*KOUT + (lane & 7)];   // 8 out-edge idx

        // gather 16 in-edge rows (lane = d); keep fp32 in regs for pooling
        float ein_r[16];
        #pragma unroll
        for (int r = 0; r < 16; ++r) {
            const int gi = __shfl(idx_l, r);
            ein_r[r] = edges[(size_t)gi * D + lane];
            eins[wave][r][lane] = f2bf(ein_r[r]);
        }
        // gather 8 out-edge rows straight into xbuf (bf16)
        #pragma unroll
        for (int r = 0; r < 8; ++r) {
            const int gi = __shfl(oidx_l, r);
            xbuf[nl0*KOUT + r][lane] = f2bf(edges[(size_t)gi * D + lane]);
        }
        if (lane < 2*KOUT) omaskf[nl0*KOUT + lane] = (float)out_mask[n0*KOUT + lane];

        // scores for both nodes in one 16x16 tile: D = Ein . Ein^T (A==B reg)
        const short8v f0 = *(const short8v*)&eins[wave][col][grp*8];
        const short8v f1 = *(const short8v*)&eins[wave][col][32 + grp*8];
        f32x4 sc = (f32x4){0.f, 0.f, 0.f, 0.f};
        sc = __builtin_amdgcn_mfma_f32_16x16x32_bf16(f0, f0, sc, 0, 0, 0);
        sc = __builtin_amdgcn_mfma_f32_16x16x32_bf16(f1, f1, sc, 0, 0, 0);

        // mask: cross-node blocks + masked keys -> -1e9   (row=grp*4+j, col)
        float s0, s1, s2, s3;
        {
            const bool kv = (mkcol > 0.f);
            #define MSK(jj, sv) { const int row = grp*4 + jj; \
                const bool ok = kv && ((row < 8) == (col < 8)); \
                sv = ok ? sc[jj] * 0.125f : -1e9f; }
            MSK(0, s0) MSK(1, s1) MSK(2, s2) MSK(3, s3)
            #undef MSK
        }
        // softmax over cols (16 lanes), 4 rows in flight
        float m0=s0, m1=s1, m2=s2, m3=s3;
        #pragma unroll
        for (int off = 1; off < 16; off <<= 1) {
            m0 = fmaxf(m0, __shfl_xor(m0, off));
            m1 = fmaxf(m1, __shfl_xor(m1, off));
            m2 = fmaxf(m2, __shfl_xor(m2, off));
            m3 = fmaxf(m3, __shfl_xor(m3, off));
        }
        float e0=__expf(s0-m0), e1=__expf(s1-m1), e2=__expf(s2-m2), e3=__expf(s3-m3);
        float t0=e0, t1=e1, t2=e2, t3=e3;
        #pragma unroll
        for (int off = 1; off < 16; off <<= 1) {
            t0 += __shfl_xor(t0, off); t1 += __shfl_xor(t1, off);
            t2 += __shfl_xor(t2, off); t3 += __shfl_xor(t3, off);
        }
        // w[col] = sum_q maskq * attn[q][col]  (query masks via shfl of mkcol)
        float wsum = __shfl(mkcol, grp*4 + 0) * (e0 / t0)
                   + __shfl(mkcol, grp*4 + 1) * (e1 / t1)
                   + __shfl(mkcol, grp*4 + 2) * (e2 / t2)
                   + __shfl(mkcol, grp*4 + 3) * (e3 / t3);
        wsum += __shfl_xor(wsum, 16);
        wsum += __shfl_xor(wsum, 32);   // every lane: w for its col's node

        // denom per col's node
        float dn = mkcol;
        dn += __shfl_xor(dn, 1); dn += __shfl_xor(dn, 2); dn += __shfl_xor(dn, 4);
        const float dnA = fmaxf(__shfl(dn, 0), 1.f);
        const float dnB = fmaxf(__shfl(dn, 8), 1.f);

        // pooled from registers (fp32), lane = d
        float pA = 0.f, pB = 0.f;
        #pragma unroll
        for (int k = 0; k < 8; ++k) {
            pA += __shfl(wsum, k)     * ein_r[k];
            pB += __shfl(wsum, 8 + k) * ein_r[8 + k];
        }
        const unsigned short pbA = f2bf(pA / dnA);
        const unsigned short pbB = f2bf(pB / dnB);
        #pragma unroll
        for (int j = 0; j < KOUT; ++j) {
            xbuf[ nl0   *KOUT + j][D + lane] = pbA;
            xbuf[(nl0+1)*KOUT + j][D + lane] = pbB;
        }
    }
    __syncthreads();

    // ---------------- Phase 2: two 64x128x128 bf16-MFMA layers ----------------
    const int rowbase = (wave >> 1) * 32;
    const int colbase = (wave & 1) * 64;
    const int l15  = lane & 15;
    const int kofs = (lane >> 4) * 8;
    const int rrow = (lane >> 4) * 4;

    #pragma unroll
    for (int layer = 0; layer < 2; ++layer) {
        const unsigned short* __restrict__ Wl = Wbf + layer * (H*H);
        const float* __restrict__ bl = layer ? b1 : b0;

        f32x4 acc[2][4];
        #pragma unroll
        for (int ct = 0; ct < 4; ++ct) {
            const float bv = bl[colbase + ct*16 + l15];
            #pragma unroll
            for (int r = 0; r < 2; ++r) acc[r][ct] = (f32x4){bv, bv, bv, bv};
        }

        #pragma unroll
        for (int ks = 0; ks < 4; ++ks) {
            short8v bf[4];
            #pragma unroll
            for (int ct = 0; ct < 4; ++ct)
                bf[ct] = *(const short8v*)&Wl[(size_t)(colbase + ct*16 + l15) * H + ks*32 + kofs];
            #pragma unroll
            for (int r = 0; r < 2; ++r) {
                const short8v a = *(const short8v*)&xbuf[rowbase + r*16 + l15][ks*32 + kofs];
                #pragma unroll
                for (int ct = 0; ct < 4; ++ct)
                    acc[r][ct] = __builtin_amdgcn_mfma_f32_16x16x32_bf16(a, bf[ct], acc[r][ct], 0, 0, 0);
            }
        }
        __syncthreads();   // all A-reads of xbuf complete
        #pragma unroll
        for (int r = 0; r < 2; ++r)
            #pragma unroll
            for (int ct = 0; ct < 4; ++ct)
                #pragma unroll
                for (int j = 0; j < 4; ++j)
                    xbuf[rowbase + r*16 + rrow + j][colbase + ct*16 + l15] =
                        f2bf(fmaxf(acc[r][ct][j], 0.f));
        __syncthreads();
    }

    // ---------------- epilogue: y = h1 . Wout + bout, masked ----------------
    {
        const int row = tid >> 2;          // 0..63
        const int kq  = tid & 3;           // k-quarter (32 each)
        float p = 0.f;
        #pragma unroll
        for (int m = 0; m < 4; ++m) {
            const int k0 = kq*32 + m*8;
            const short8v hv = *(const short8v*)&xbuf[row][k0];
            const float4 w0 = *(const float4*)&Wout[k0];
            const float4 w1 = *(const float4*)&Wout[k0 + 4];
            union { unsigned u; float f; } c;
            float acc8 = 0.f;
            c.u = ((unsigned)(unsigned short)hv[0]) << 16; acc8 += c.f * w0.x;
            c.u = ((unsigned)(unsigned short)hv[1]) << 16; acc8 += c.f * w0.y;
            c.u = ((unsigned)(unsigned short)hv[2]) << 16; acc8 += c.f * w0.z;
            c.u = ((unsigned)(unsigned short)hv[3]) << 16; acc8 += c.f * w0.w;
            c.u = ((unsigned)(unsigned short)hv[4]) << 16; acc8 += c.f * w1.x;
            c.u = ((unsigned)(unsigned short)hv[5]) << 16; acc8 += c.f * w1.y;
            c.u = ((unsigned)(unsigned short)hv[6]) << 16; acc8 += c.f * w1.z;
            c.u = ((unsigned)(unsigned short)hv[7]) << 16; acc8 += c.f * w1.w;
            p += acc8;
        }
        p += __shfl_xor(p, 1);
        p += __shfl_xor(p, 2);
        if (kq == 0) {
            const long long grow = (long long)nodeBase * KOUT + row;
            if (grow < (long long)N * KOUT)
                out[grow] = (p + bout[0]) * omaskf[row];
        }
    }
}

extern "C" void kernel_launch(void* const* d_in, const int* in_sizes, int n_in,
                              void* d_out, int out_size, void* d_ws, size_t ws_size,
                              hipStream_t stream)
{
    const float* edges  = (const float*)d_in[0];
    const int* in_idx   = (const int*)d_in[1];
    const int* in_mask  = (const int*)d_in[2];
    const int* out_idx  = (const int*)d_in[3];
    const int* out_mask = (const int*)d_in[4];
    const float* W0   = (const float*)d_in[5];
    const float* b0   = (const float*)d_in[6];
    const float* W1   = (const float*)d_in[7];
    const float* b1   = (const float*)d_in[8];
    const float* Wout = (const float*)d_in[9];
    const float* bout = (const float*)d_in[10];
    float* out = (float*)d_out;
    unsigned short* Wbf = (unsigned short*)d_ws;   // 2*128*128 bf16 = 64 KB

    const int nNodes = in_sizes[1] / KIN;               // 200000
    convert_w_kernel<<<(2*H*H + 255) / 256, 256, 0, stream>>>(W0, W1, Wbf);
    const int grid = (nNodes + NPB - 1) / NPB;          // 12500
    encoder_kernel<<<grid, THREADS, 0, stream>>>(
        edges, in_idx, in_mask, out_idx, out_mask,
        b0, b1, Wout, bout, Wbf, out, nNodes);
}